// Round 10
// baseline (185.867 us; speedup 1.0000x reference)
//
#include <hip/hip_runtime.h>

// Trilinear interpolation of a 128^3 x 16 latent grid at 2M random points.
// 3-phase spatial counting sort:
//   A1: counting-sort points into 64 super-bins (segments in d_out, which is
//       fully overwritten by B afterwards).
//   A2: per super-bin, counting-sort its segment into 256 children -> 16384
//       fine bins (16x32x32; 8x4x4 grid cells each) in d_ws.
//   B : DIRECT-GATHER per fine bin (no LDS): the bin's 9x5x5-row latent
//       footprint is only 14.4 KB, so gathers hit L1/L2; zero LDS -> 8
//       blocks/CU, no barriers, latency hidden by TLP. XCD-bijective block
//       swizzle keeps each XCD's slab of bins L2-resident.
// Spill list + cleanup kernel guard the (>5 sigma) capacity overflow paths.

constexpr int   GRID_RES   = 128;
constexpr int   LATENT_DIM = 16;
constexpr float SCALE      = 126.0f;          // GRID_RES - 2

constexpr int NSUPER    = 64;                  // 4x4x4
constexpr int NCHILD    = 256;                 // 4x8x8 per super
constexpr int NFINE     = NSUPER * NCHILD;     // 16384 (16x32x32)
constexpr int CAP_F     = 192;                 // mean 128, sigma ~11.3
constexpr int SPILL_CAP = 16384;
constexpr int NXCD      = 8;

// d_ws layout
constexpr size_t SCUR_OFF     = 0;             // 64 u32
constexpr size_t FCUR_OFF     = 1024;          // 16384 u32
constexpr size_t SPILLCUR_OFF = 66560;         // 1 u32
constexpr size_t CUR_BYTES    = 69632;         // memset region
constexpr size_t FINE_OFF     = CUR_BYTES;
constexpr size_t FINE_BYTES   = (size_t)NFINE * CAP_F * 16;
constexpr size_t SPILL_OFF    = FINE_OFF + FINE_BYTES;
constexpr size_t WS_NEEDED    = SPILL_OFF + (size_t)SPILL_CAP * 16;

typedef float fvec4 __attribute__((ext_vector_type(4)));

// ---- helpers ----------------------------------------------------------------

__device__ __forceinline__ void fine_bin(float x, float y, float z,
                                         int* s, int* c) {
    const int lx = min(max((int)floorf(x * SCALE), 0), 125);
    const int ly = min(max((int)floorf(y * SCALE), 0), 125);
    const int lz = min(max((int)floorf(z * SCALE), 0), 125);
    const int fbx = lx >> 3;   // [0,16)
    const int fby = ly >> 2;   // [0,32)
    const int fbz = lz >> 2;   // [0,32)
    *s = ((fbx >> 2) << 4) | ((fby >> 3) << 2) | (fbz >> 3);           // [0,64)
    *c = ((fbx & 3) << 6) | ((fby & 7) << 3) | (fbz & 7);              // [0,256)
}

__device__ __forceinline__ void corner_setup(
    float sx, float sy, float sz,
    int cx[2], int cy[2], int cz[2],
    float fx[2], float fy[2], float fz[2])
{
    const float bx = floorf(sx), by = floorf(sy), bz = floorf(sz);
    const int ix = (int)bx, iy = (int)by, iz = (int)bz;
    const float wbx = sx - bx, wby = sy - by, wbz = sz - bz;
    cx[0] = min(max(ix,     0), GRID_RES - 1);
    cx[1] = min(max(ix + 1, 0), GRID_RES - 1);
    cy[0] = min(max(iy,     0), GRID_RES - 1);
    cy[1] = min(max(iy + 1, 0), GRID_RES - 1);
    cz[0] = min(max(iz,     0), GRID_RES - 1);
    cz[1] = min(max(iz + 1, 0), GRID_RES - 1);
    fx[0] = 1.0f - wbx; fx[1] = wbx;
    fy[0] = 1.0f - wby; fy[1] = wby;
    fz[0] = 1.0f - wbz; fz[1] = wbz;
}

__device__ __forceinline__ fvec4 trilerp_q(
    const float* __restrict__ latents,
    const int cx[2], const int cy[2], const int cz[2],
    const float fx[2], const float fy[2], const float fz[2], int q)
{
    fvec4 acc = (fvec4)(0.0f);
    #pragma unroll
    for (int ox = 0; ox < 2; ++ox)
      #pragma unroll
      for (int oy = 0; oy < 2; ++oy)
        #pragma unroll
        for (int oz = 0; oz < 2; ++oz) {
            const int flat = cx[ox] * (GRID_RES * GRID_RES) + cy[oy] * GRID_RES + cz[oz];
            const float w = fx[ox] * fy[oy] * fz[oz];
            const fvec4 f = *reinterpret_cast<const fvec4*>(
                latents + (size_t)flat * LATENT_DIM + q * 4);
            acc += w * f;
        }
    return acc;
}

// ---- A1: counting-sort into 64 super-bins (segments in d_out) ---------------

__global__ __launch_bounds__(256) void binA1(
    const float* __restrict__ pts, int n_pts,
    unsigned* __restrict__ scur, fvec4* __restrict__ superSeg, int cap_s,
    unsigned* __restrict__ spillcur, fvec4* __restrict__ spillSeg)
{
    __shared__ unsigned cnt[NSUPER], base[NSUPER], off[NSUPER];
    const int t = threadIdx.x;
    if (t < NSUPER) { cnt[t] = 0; off[t] = 0; }
    __syncthreads();

    const int chunk = (n_pts + gridDim.x - 1) / gridDim.x;
    const int lo = blockIdx.x * chunk;
    const int hi = min(lo + chunk, n_pts);

    for (int p = lo + t; p < hi; p += 256) {
        int s, c;
        fine_bin(pts[3*p], pts[3*p+1], pts[3*p+2], &s, &c);
        atomicAdd(&cnt[s], 1u);
    }
    __syncthreads();
    if (t < NSUPER) base[t] = atomicAdd(&scur[t], cnt[t]);
    __syncthreads();
    for (int p = lo + t; p < hi; p += 256) {
        const float x = pts[3*p], y = pts[3*p+1], z = pts[3*p+2];
        int s, c;
        fine_bin(x, y, z, &s, &c);
        const unsigned slot = base[s] + atomicAdd(&off[s], 1u);
        fvec4 tp; tp.x = x; tp.y = y; tp.z = z; tp.w = __uint_as_float((unsigned)p);
        if (slot < (unsigned)cap_s) {
            superSeg[(size_t)s * cap_s + slot] = tp;
        } else {                                   // ~impossible; keep correct
            const unsigned sp = atomicAdd(spillcur, 1u);
            if (sp < (unsigned)SPILL_CAP) spillSeg[sp] = tp;
        }
    }
}

// ---- A2: refine each super-bin into its 256 children ------------------------

__global__ __launch_bounds__(256) void binA2(
    const fvec4* __restrict__ superSeg, int cap_s,
    const unsigned* __restrict__ scur,
    unsigned* __restrict__ fcur, fvec4* __restrict__ fineSeg,
    unsigned* __restrict__ spillcur, fvec4* __restrict__ spillSeg)
{
    constexpr int SLICES = 8;
    const int super = blockIdx.x / SLICES;
    const int slice = blockIdx.x % SLICES;
    const unsigned n = min(scur[super], (unsigned)cap_s);
    const unsigned lo = (unsigned)(((unsigned long long)n * slice) / SLICES);
    const unsigned hi = (unsigned)(((unsigned long long)n * (slice + 1)) / SLICES);

    __shared__ unsigned cnt[NCHILD], base[NCHILD], off[NCHILD];
    const int t = threadIdx.x;
    cnt[t] = 0; off[t] = 0;          // NCHILD == blockDim
    __syncthreads();

    for (unsigned i = lo + t; i < hi; i += 256) {
        const fvec4 tp = superSeg[(size_t)super * cap_s + i];
        int s, c;
        fine_bin(tp.x, tp.y, tp.z, &s, &c);
        atomicAdd(&cnt[c], 1u);
    }
    __syncthreads();
    base[t] = atomicAdd(&fcur[super * NCHILD + t], cnt[t]);
    __syncthreads();
    for (unsigned i = lo + t; i < hi; i += 256) {
        const fvec4 tp = superSeg[(size_t)super * cap_s + i];
        int s, c;
        fine_bin(tp.x, tp.y, tp.z, &s, &c);
        const unsigned slot = base[c] + atomicAdd(&off[c], 1u);
        if (slot < (unsigned)CAP_F) {
            fineSeg[(size_t)(super * NCHILD + c) * CAP_F + slot] = tp;
        } else {
            const unsigned sp = atomicAdd(spillcur, 1u);
            if (sp < (unsigned)SPILL_CAP) spillSeg[sp] = tp;
        }
    }
}

// ---- B: direct-gather per fine bin (no LDS) ---------------------------------
// Footprint/bin = 9x5x5 rows = 14.4 KB -> L1/L2-resident. XCD-bijective
// swizzle: XCD k owns fids [k*2048, (k+1)*2048) = a contiguous spatial slab.

__global__ __launch_bounds__(256) void binB(
    const fvec4* __restrict__ fineSeg, const unsigned* __restrict__ fcur,
    const float* __restrict__ latents, float* __restrict__ out)
{
    const int orig = blockIdx.x;
    const int fid  = (orig & (NXCD - 1)) * (NFINE / NXCD) + (orig >> 3);

    const int t = threadIdx.x;
    const int q = t & 3, lp = t >> 2;

    const int n = (int)min(fcur[fid], (unsigned)CAP_F);   // n <= 192 = 3*64
    const fvec4* seg = fineSeg + (size_t)fid * CAP_F;

    // early tuple loads (clamped addresses; latency overlaps following ALU)
    const int hi = max(n - 1, 0);
    const fvec4 tp0 = __builtin_nontemporal_load(&seg[min(lp,       hi)]);
    const fvec4 tp1 = __builtin_nontemporal_load(&seg[min(lp +  64, hi)]);
    const fvec4 tp2 = __builtin_nontemporal_load(&seg[min(lp + 128, hi)]);

    #pragma unroll
    for (int k = 0; k < 3; ++k) {
        if (lp + k * 64 < n) {
            const fvec4 tp = (k == 0) ? tp0 : (k == 1) ? tp1 : tp2;
            const unsigned idx = __float_as_uint(tp.w);
            int cx[2], cy[2], cz[2]; float fx[2], fy[2], fz[2];
            corner_setup(tp.x * SCALE, tp.y * SCALE, tp.z * SCALE,
                         cx, cy, cz, fx, fy, fz);
            const fvec4 acc = trilerp_q(latents, cx, cy, cz, fx, fy, fz, q);
            __builtin_nontemporal_store(acc,
                reinterpret_cast<fvec4*>(out + (size_t)idx * LATENT_DIM + q * 4));
        }
    }
}

// ---- spill cleanup (normally n == 0) ----------------------------------------

__global__ __launch_bounds__(256) void spillK(
    const fvec4* __restrict__ spillSeg, const unsigned* __restrict__ spillcur,
    const float* __restrict__ latents, float* __restrict__ out)
{
    const unsigned n = min(*spillcur, (unsigned)SPILL_CAP);
    for (unsigned i = blockIdx.x * 256 + threadIdx.x; i < n; i += gridDim.x * 256) {
        const fvec4 tp = spillSeg[i];
        const unsigned idx = __float_as_uint(tp.w);
        int cx[2], cy[2], cz[2]; float fx[2], fy[2], fz[2];
        corner_setup(tp.x * SCALE, tp.y * SCALE, tp.z * SCALE, cx, cy, cz, fx, fy, fz);
        #pragma unroll
        for (int q = 0; q < 4; ++q) {
            const fvec4 acc = trilerp_q(latents, cx, cy, cz, fx, fy, fz, q);
            *reinterpret_cast<fvec4*>(out + (size_t)idx * LATENT_DIM + q * 4) = acc;
        }
    }
}

// ---- fallback: direct version ----------------------------------------------

__global__ __launch_bounds__(256) void trilerp_direct(
    const float* __restrict__ pts, const float* __restrict__ latents,
    float* __restrict__ out, int n_pts)
{
    const int tid = blockIdx.x * blockDim.x + threadIdx.x;
    const int p = tid >> 2;
    const int q = tid & 3;
    if (p >= n_pts) return;
    int cx[2], cy[2], cz[2]; float fx[2], fy[2], fz[2];
    corner_setup(pts[3*p] * SCALE, pts[3*p+1] * SCALE, pts[3*p+2] * SCALE,
                 cx, cy, cz, fx, fy, fz);
    const fvec4 acc = trilerp_q(latents, cx, cy, cz, fx, fy, fz, q);
    *reinterpret_cast<fvec4*>(out + (size_t)p * LATENT_DIM + q * 4) = acc;
}

// ---- launch -----------------------------------------------------------------

extern "C" void kernel_launch(void* const* d_in, const int* in_sizes, int n_in,
                              void* d_out, int out_size, void* d_ws, size_t ws_size,
                              hipStream_t stream) {
    const float* pts     = (const float*)d_in[0];
    const float* latents = (const float*)d_in[1];
    float* out = (float*)d_out;
    const int n_pts = in_sizes[0] / 3;

    const int cap_s = (int)(((size_t)out_size * 4) / (NSUPER * 16));  // tuples/super seg

    if (ws_size < WS_NEEDED || cap_s * (size_t)NSUPER * 16 > (size_t)out_size * 4 ||
        (size_t)cap_s < (size_t)n_pts / 16) {
        const int total = n_pts * 4;
        trilerp_direct<<<(total + 255) / 256, 256, 0, stream>>>(pts, latents, out, n_pts);
        return;
    }

    unsigned* scur     = (unsigned*)((char*)d_ws + SCUR_OFF);
    unsigned* fcur     = (unsigned*)((char*)d_ws + FCUR_OFF);
    unsigned* spillcur = (unsigned*)((char*)d_ws + SPILLCUR_OFF);
    fvec4*    fineSeg  = (fvec4*)((char*)d_ws + FINE_OFF);
    fvec4*    spillSeg = (fvec4*)((char*)d_ws + SPILL_OFF);
    fvec4*    superSeg = (fvec4*)d_out;                 // reused as scratch

    hipMemsetAsync(d_ws, 0, CUR_BYTES, stream);
    binA1<<<512, 256, 0, stream>>>(pts, n_pts, scur, superSeg, cap_s,
                                   spillcur, spillSeg);
    binA2<<<NSUPER * 8, 256, 0, stream>>>(superSeg, cap_s, scur,
                                          fcur, fineSeg, spillcur, spillSeg);
    binB<<<NFINE, 256, 0, stream>>>(fineSeg, fcur, latents, out);
    spillK<<<16, 256, 0, stream>>>(spillSeg, spillcur, latents, out);
}

// Round 11
// 144.894 us; speedup vs baseline: 1.2828x; 1.2828x over previous
//
#include <hip/hip_runtime.h>

// Trilinear interpolation of a 128^3 x 16 latent grid at 2M random points.
// 3-phase spatial counting sort, WAVE-PRIVATE phase B (zero barriers):
//   A1: counting-sort points into 512 super-bins (8x8x8), segments in d_out
//       (fully overwritten by B afterwards).
//   A2: per super-bin, counting-sort its segment into 64 children -> 32768
//       fine bins (32^3; 4x4x4 grid cells each) in d_ws.
//   B : one bin per WAVE. Each wave DMA-stages its bin's 5x5x5-row latent
//       tile (8 KB) into its private LDS slice via global_load_lds (source-
//       swizzled for bank spread), prefetches all tuples, waits once on its
//       own vmcnt, computes. No __syncthreads anywhere -> latency hidden by
//       20 independent waves/CU.
// Spill list + cleanup kernel guard the capacity overflow paths.

constexpr int   GRID_RES   = 128;
constexpr int   LATENT_DIM = 16;
constexpr float SCALE      = 126.0f;          // GRID_RES - 2

constexpr int NSUPER    = 512;                 // 8x8x8
constexpr int NCHILD    = 64;                  // 4x4x4 per super
constexpr int NFINE     = NSUPER * NCHILD;     // 32768 (32^3)
constexpr int CAP_F     = 96;                  // mean ~64, sigma ~8
constexpr int SPILL_CAP = 16384;
constexpr int NROWS     = 125;                 // 5x5x5 staged latent rows
constexpr int NXCD      = 8;

// d_ws layout
constexpr size_t SCUR_OFF     = 0;             // 512 u32
constexpr size_t FCUR_OFF     = 2048;          // 32768 u32
constexpr size_t SPILLCUR_OFF = 133120;        // 1 u32
constexpr size_t CUR_BYTES    = 134144;        // memset region
constexpr size_t FINE_OFF     = CUR_BYTES;
constexpr size_t FINE_BYTES   = (size_t)NFINE * CAP_F * 16;   // 48 MB
constexpr size_t SPILL_OFF    = FINE_OFF + FINE_BYTES;
constexpr size_t WS_NEEDED    = SPILL_OFF + (size_t)SPILL_CAP * 16;

typedef float fvec4 __attribute__((ext_vector_type(4)));
typedef const __attribute__((address_space(1))) unsigned int* gptr_t;
typedef __attribute__((address_space(3))) unsigned int*       lptr_t;

// ---- helpers ----------------------------------------------------------------

__device__ __forceinline__ void fine_bin(float x, float y, float z,
                                         int* s, int* c) {
    const int lx = min(max((int)floorf(x * SCALE), 0), 125);
    const int ly = min(max((int)floorf(y * SCALE), 0), 125);
    const int lz = min(max((int)floorf(z * SCALE), 0), 125);
    const int fbx = lx >> 2;   // [0,32)
    const int fby = ly >> 2;   // [0,32)
    const int fbz = lz >> 2;   // [0,32)
    *s = ((fbx >> 2) << 6) | ((fby >> 2) << 3) | (fbz >> 2);   // [0,512)
    *c = ((fbx & 3) << 4) | ((fby & 3) << 2) | (fbz & 3);      // [0,64)
}

__device__ __forceinline__ void corner_setup(
    float sx, float sy, float sz,
    int cx[2], int cy[2], int cz[2],
    float fx[2], float fy[2], float fz[2])
{
    const float bx = floorf(sx), by = floorf(sy), bz = floorf(sz);
    const int ix = (int)bx, iy = (int)by, iz = (int)bz;
    const float wbx = sx - bx, wby = sy - by, wbz = sz - bz;
    cx[0] = min(max(ix,     0), GRID_RES - 1);
    cx[1] = min(max(ix + 1, 0), GRID_RES - 1);
    cy[0] = min(max(iy,     0), GRID_RES - 1);
    cy[1] = min(max(iy + 1, 0), GRID_RES - 1);
    cz[0] = min(max(iz,     0), GRID_RES - 1);
    cz[1] = min(max(iz + 1, 0), GRID_RES - 1);
    fx[0] = 1.0f - wbx; fx[1] = wbx;
    fy[0] = 1.0f - wby; fy[1] = wby;
    fz[0] = 1.0f - wbz; fz[1] = wbz;
}

__device__ __forceinline__ fvec4 trilerp_q(
    const float* __restrict__ latents,
    const int cx[2], const int cy[2], const int cz[2],
    const float fx[2], const float fy[2], const float fz[2], int q)
{
    fvec4 acc = (fvec4)(0.0f);
    #pragma unroll
    for (int ox = 0; ox < 2; ++ox)
      #pragma unroll
      for (int oy = 0; oy < 2; ++oy)
        #pragma unroll
        for (int oz = 0; oz < 2; ++oz) {
            const int flat = cx[ox] * (GRID_RES * GRID_RES) + cy[oy] * GRID_RES + cz[oz];
            const float w = fx[ox] * fy[oy] * fz[oz];
            const fvec4 f = *reinterpret_cast<const fvec4*>(
                latents + (size_t)flat * LATENT_DIM + q * 4);
            acc += w * f;
        }
    return acc;
}

// ---- A1: counting-sort into 512 super-bins (segments in d_out) --------------

__global__ __launch_bounds__(256) void binA1(
    const float* __restrict__ pts, int n_pts,
    unsigned* __restrict__ scur, fvec4* __restrict__ superSeg, int cap_s,
    unsigned* __restrict__ spillcur, fvec4* __restrict__ spillSeg)
{
    __shared__ unsigned cnt[NSUPER], base[NSUPER], off[NSUPER];
    const int t = threadIdx.x;
    for (int i = t; i < NSUPER; i += 256) { cnt[i] = 0; off[i] = 0; }
    __syncthreads();

    const int chunk = (n_pts + gridDim.x - 1) / gridDim.x;
    const int lo = blockIdx.x * chunk;
    const int hi = min(lo + chunk, n_pts);

    for (int p = lo + t; p < hi; p += 256) {
        int s, c;
        fine_bin(pts[3*p], pts[3*p+1], pts[3*p+2], &s, &c);
        atomicAdd(&cnt[s], 1u);
    }
    __syncthreads();
    for (int i = t; i < NSUPER; i += 256) base[i] = atomicAdd(&scur[i], cnt[i]);
    __syncthreads();
    for (int p = lo + t; p < hi; p += 256) {
        const float x = pts[3*p], y = pts[3*p+1], z = pts[3*p+2];
        int s, c;
        fine_bin(x, y, z, &s, &c);
        const unsigned slot = base[s] + atomicAdd(&off[s], 1u);
        fvec4 tp; tp.x = x; tp.y = y; tp.z = z; tp.w = __uint_as_float((unsigned)p);
        if (slot < (unsigned)cap_s) {
            superSeg[(size_t)s * cap_s + slot] = tp;
        } else {                                   // ~impossible; keep correct
            const unsigned sp = atomicAdd(spillcur, 1u);
            if (sp < (unsigned)SPILL_CAP) spillSeg[sp] = tp;
        }
    }
}

// ---- A2: refine each super-bin into its 64 children -------------------------

__global__ __launch_bounds__(256) void binA2(
    const fvec4* __restrict__ superSeg, int cap_s,
    const unsigned* __restrict__ scur,
    unsigned* __restrict__ fcur, fvec4* __restrict__ fineSeg,
    unsigned* __restrict__ spillcur, fvec4* __restrict__ spillSeg)
{
    constexpr int SLICES = 2;
    const int super = blockIdx.x / SLICES;
    const int slice = blockIdx.x % SLICES;
    const unsigned n = min(scur[super], (unsigned)cap_s);
    const unsigned lo = (unsigned)(((unsigned long long)n * slice) / SLICES);
    const unsigned hi = (unsigned)(((unsigned long long)n * (slice + 1)) / SLICES);

    __shared__ unsigned cnt[NCHILD], base[NCHILD], off[NCHILD];
    const int t = threadIdx.x;
    if (t < NCHILD) { cnt[t] = 0; off[t] = 0; }
    __syncthreads();

    for (unsigned i = lo + t; i < hi; i += 256) {
        const fvec4 tp = superSeg[(size_t)super * cap_s + i];
        int s, c;
        fine_bin(tp.x, tp.y, tp.z, &s, &c);
        atomicAdd(&cnt[c], 1u);
    }
    __syncthreads();
    if (t < NCHILD) base[t] = atomicAdd(&fcur[super * NCHILD + t], cnt[t]);
    __syncthreads();
    for (unsigned i = lo + t; i < hi; i += 256) {
        const fvec4 tp = superSeg[(size_t)super * cap_s + i];
        int s, c;
        fine_bin(tp.x, tp.y, tp.z, &s, &c);
        const unsigned slot = base[c] + atomicAdd(&off[c], 1u);
        if (slot < (unsigned)CAP_F) {
            fineSeg[(size_t)(super * NCHILD + c) * CAP_F + slot] = tp;
        } else {
            const unsigned sp = atomicAdd(spillcur, 1u);
            if (sp < (unsigned)SPILL_CAP) spillSeg[sp] = tp;
        }
    }
}

// ---- B: one bin per wave, wave-private LDS slice, no barriers ---------------
// Bin covers cells [bx*4,+4)^3; staged tile 5x5x5 = 125 rows (64 B each) in an
// 8 KB wave-private LDS slice. DMA-linear layout with SOURCE swizzle: LDS unit
// u = r*4+j holds quarter (j+r)&3 of row r; reader finds quarter q of row r at
// unit r*4+((q-r)&3) -> read bank windows cycle over 8 slots (~2-way, free).

__global__ __launch_bounds__(256, 5) void binB(
    const fvec4* __restrict__ fineSeg, const unsigned* __restrict__ fcur,
    const float* __restrict__ latents, float* __restrict__ out)
{
    __shared__ __align__(16) float lat[4][2048];   // 8 KB per wave

    const int orig = blockIdx.x;                   // 8192 blocks
    const int blk  = (orig & (NXCD - 1)) * (gridDim.x / NXCD) + (orig >> 3);

    const int t    = threadIdx.x;
    const int wave = t >> 6, lane = t & 63;
    const int q    = lane & 3, g = lane >> 2;      // q: feature quarter, g: point slot

    const int fid   = blk * 4 + wave;
    const int super = fid >> 6, c = fid & 63;
    const int bx = (((super >> 6)      ) << 2) | (c >> 4);        // [0,32)
    const int by = (((super >> 3) & 7) << 2) | ((c >> 2) & 3);    // [0,32)
    const int bz = (((super      ) & 7) << 2) | (c & 3);          // [0,32)

    const int n = (int)min(fcur[fid], (unsigned)CAP_F);   // n <= 96 = 6*16
    const fvec4* seg = fineSeg + (size_t)fid * CAP_F;
    float* lw = &lat[wave][0];

    // ---- wave-level DMA stage: 8 rounds x 64 lanes of 16 B ------------------
    #pragma unroll
    for (int k = 0; k < 8; ++k) {
        const int u  = k * 64 + lane;
        const int uc = min(u, NROWS * 4 - 1);          // clamp tail into pad
        const int r  = uc >> 2, j = uc & 3;
        const int qs = (j + r) & 3;                    // source-side swizzle
        const int dx = r / 25, rem = r - dx * 25, dy = rem / 5, dz = rem - dy * 5;
        const int gx = min(bx * 4 + dx, 127);
        const int gy = min(by * 4 + dy, 127);
        const int gz = min(bz * 4 + dz, 127);
        const float* src = latents
            + ((size_t)(((gx << 7) | gy) << 7 | gz)) * LATENT_DIM + qs * 4;
        float* dst = lw + k * 256;                     // wave-uniform base; HW adds lane*16B
        __builtin_amdgcn_global_load_lds((gptr_t)(const void*)src,
                                         (lptr_t)(void*)dst, 16, 0, 0);
    }

    // ---- prefetch all tuples (clamped addresses, always issued) -------------
    const int hi = max(n - 1, 0);
    fvec4 tp[6];
    #pragma unroll
    for (int k = 0; k < 6; ++k)
        tp[k] = __builtin_nontemporal_load(&seg[min(k * 16 + g, hi)]);

    // ---- single wave-level wait; no barriers --------------------------------
    asm volatile("s_waitcnt vmcnt(0)" ::: "memory");
    __builtin_amdgcn_sched_barrier(0);

    // ---- compute ------------------------------------------------------------
    #pragma unroll
    for (int k = 0; k < 6; ++k) {
        if (k * 16 + g < n) {
            const fvec4 tpv = tp[k];
            const unsigned idx = __float_as_uint(tpv.w);
            const float sxv = tpv.x * SCALE, syv = tpv.y * SCALE, szv = tpv.z * SCALE;
            const float bxf = floorf(sxv), byf = floorf(syv), bzf = floorf(szv);
            const int lx = (int)bxf - bx * 4;           // [0,3]
            const int ly = (int)byf - by * 4;           // [0,3]
            const int lz = (int)bzf - bz * 4;           // [0,3]
            const float wbx = sxv - bxf, wby = syv - byf, wbz = szv - bzf;
            const float fx[2] = {1.0f - wbx, wbx};
            const float fy[2] = {1.0f - wby, wby};
            const float fz[2] = {1.0f - wbz, wbz};

            fvec4 acc = (fvec4)(0.0f);
            #pragma unroll
            for (int ox = 0; ox < 2; ++ox)
              #pragma unroll
              for (int oy = 0; oy < 2; ++oy)
                #pragma unroll
                for (int oz = 0; oz < 2; ++oz) {
                    const int rr = (lx + ox) * 25 + (ly + oy) * 5 + (lz + oz);
                    const int unit = rr * 4 + ((q - rr) & 3);
                    const fvec4 f = *reinterpret_cast<const fvec4*>(&lw[unit * 4]);
                    acc += (fx[ox] * fy[oy] * fz[oz]) * f;
                }

            __builtin_nontemporal_store(acc,
                reinterpret_cast<fvec4*>(out + (size_t)idx * LATENT_DIM + q * 4));
        }
    }
}

// ---- spill cleanup (normally tiny) ------------------------------------------

__global__ __launch_bounds__(256) void spillK(
    const fvec4* __restrict__ spillSeg, const unsigned* __restrict__ spillcur,
    const float* __restrict__ latents, float* __restrict__ out)
{
    const unsigned n = min(*spillcur, (unsigned)SPILL_CAP);
    for (unsigned i = blockIdx.x * 256 + threadIdx.x; i < n; i += gridDim.x * 256) {
        const fvec4 tp = spillSeg[i];
        const unsigned idx = __float_as_uint(tp.w);
        int cx[2], cy[2], cz[2]; float fx[2], fy[2], fz[2];
        corner_setup(tp.x * SCALE, tp.y * SCALE, tp.z * SCALE, cx, cy, cz, fx, fy, fz);
        #pragma unroll
        for (int q = 0; q < 4; ++q) {
            const fvec4 acc = trilerp_q(latents, cx, cy, cz, fx, fy, fz, q);
            *reinterpret_cast<fvec4*>(out + (size_t)idx * LATENT_DIM + q * 4) = acc;
        }
    }
}

// ---- fallback: direct version ----------------------------------------------

__global__ __launch_bounds__(256) void trilerp_direct(
    const float* __restrict__ pts, const float* __restrict__ latents,
    float* __restrict__ out, int n_pts)
{
    const int tid = blockIdx.x * blockDim.x + threadIdx.x;
    const int p = tid >> 2;
    const int q = tid & 3;
    if (p >= n_pts) return;
    int cx[2], cy[2], cz[2]; float fx[2], fy[2], fz[2];
    corner_setup(pts[3*p] * SCALE, pts[3*p+1] * SCALE, pts[3*p+2] * SCALE,
                 cx, cy, cz, fx, fy, fz);
    const fvec4 acc = trilerp_q(latents, cx, cy, cz, fx, fy, fz, q);
    *reinterpret_cast<fvec4*>(out + (size_t)p * LATENT_DIM + q * 4) = acc;
}

// ---- launch -----------------------------------------------------------------

extern "C" void kernel_launch(void* const* d_in, const int* in_sizes, int n_in,
                              void* d_out, int out_size, void* d_ws, size_t ws_size,
                              hipStream_t stream) {
    const float* pts     = (const float*)d_in[0];
    const float* latents = (const float*)d_in[1];
    float* out = (float*)d_out;
    const int n_pts = in_sizes[0] / 3;

    const int cap_s = (int)(((size_t)out_size * 4) / (NSUPER * 16));  // tuples/super seg

    if (ws_size < WS_NEEDED || cap_s * (size_t)NSUPER * 16 > (size_t)out_size * 4 ||
        (size_t)cap_s < (size_t)n_pts / 128) {
        const int total = n_pts * 4;
        trilerp_direct<<<(total + 255) / 256, 256, 0, stream>>>(pts, latents, out, n_pts);
        return;
    }

    unsigned* scur     = (unsigned*)((char*)d_ws + SCUR_OFF);
    unsigned* fcur     = (unsigned*)((char*)d_ws + FCUR_OFF);
    unsigned* spillcur = (unsigned*)((char*)d_ws + SPILLCUR_OFF);
    fvec4*    fineSeg  = (fvec4*)((char*)d_ws + FINE_OFF);
    fvec4*    spillSeg = (fvec4*)((char*)d_ws + SPILL_OFF);
    fvec4*    superSeg = (fvec4*)d_out;                 // reused as scratch

    hipMemsetAsync(d_ws, 0, CUR_BYTES, stream);
    binA1<<<256, 256, 0, stream>>>(pts, n_pts, scur, superSeg, cap_s,
                                   spillcur, spillSeg);
    binA2<<<NSUPER * 2, 256, 0, stream>>>(superSeg, cap_s, scur,
                                          fcur, fineSeg, spillcur, spillSeg);
    binB<<<NFINE / 4, 256, 0, stream>>>(fineSeg, fcur, latents, out);
    spillK<<<16, 256, 0, stream>>>(spillSeg, spillcur, latents, out);
}